// Round 2
// baseline (803.612 us; speedup 1.0000x reference)
//
#include <hip/hip_runtime.h>

// ---------------------------------------------------------------------------
// MultiHeadsAttention: X[4,2048,1024] -> ctx[4,2048,1024], q[4,16,2048,64],
// k[4,16,2048,64] (q,k post-RoPE). fp32 in/out, bf16 MFMA internally.
// Round 10: attn is latency-chain bound (per-SIMD VALU ~25%, MFMA ~20%,
// nothing saturated; VALUBusy 62% is CU-level OR). Shorten the per-iter
// serial chain, move work to the idle matrix pipe (attn only):
//  (a) psum via ones-row MFMA (A row0=1): removes 24 VALU adds/iter from
//      the softmax chain; +4 MFMA/iter on the ~19%-busy matrix pipe.
//      End reduce becomes a single __shfl from row-0 lanes.
//  (b) V-frag rolling prefetch: ct=0 frags loaded before softmax (latency
//      hidden under exp), ct+1 prefetched inside the PV loop.
//  (c) mask prefetched with next tile's K/V global loads (reg-resident).
//  (d) exp2 via raw v_exp_f32 asm (guaranteed single-instruction).
// ---------------------------------------------------------------------------

#define B_  4
#define S_  2048
#define H_  16
#define D_  64
#define HID 1024
#define M_  (B_ * S_)          // 8192

typedef __attribute__((ext_vector_type(8))) short    bf16x8;
typedef __attribute__((ext_vector_type(4))) float    f32x4;
typedef __attribute__((ext_vector_type(4))) unsigned short u16x4;
typedef __attribute__((ext_vector_type(8))) unsigned short u16x8;
typedef __attribute__((ext_vector_type(2))) unsigned u32x2;

__device__ __forceinline__ unsigned short f2bf(float f) {
    union { float f; unsigned u; } v; v.f = f;
    unsigned r = v.u + 0x7fffu + ((v.u >> 16) & 1u);
    return (unsigned short)(r >> 16);
}

__device__ __forceinline__ void async16(const unsigned short* g, unsigned short* l) {
    __builtin_amdgcn_global_load_lds(
        (const __attribute__((address_space(1))) void*)g,
        (__attribute__((address_space(3))) void*)l, 16, 0, 0);
}

__device__ __forceinline__ float fast_exp2(float x) {
    float r;
    asm("v_exp_f32 %0, %1" : "=v"(r) : "v"(x));
    return r;
}

// ---------------------------------------------------------------------------
// Kernel 0: RoPE tables -> d_out ctx region (overwritten later by attn).
// ---------------------------------------------------------------------------
__global__ __launch_bounds__(256) void rope_table_kernel(float* __restrict__ tab)
{
    int i = blockIdx.x * 256 + threadIdx.x;     // 0 .. 131071
    int s = i >> 6, d = i & 63;
    const float NEG_LN1E4_32 = -0.28782313662425576f;  // -ln(10000)/32
    float freq = __expf(NEG_LN1E4_32 * (float)(d >> 1));
    float ang = (float)s * freq;
    tab[i]          = cosf(ang);
    tab[131072 + i] = sinf(ang);
}

// ---------------------------------------------------------------------------
// Kernel 1: cast X fp32 -> bf16
// ---------------------------------------------------------------------------
__global__ __launch_bounds__(256) void cast_x_kernel(
    const float* __restrict__ X, unsigned short* __restrict__ Xb)
{
    int i = (blockIdx.x * 256 + threadIdx.x) * 4;
    float4 v = *(const float4*)(X + i);
    u16x4 o;
    o[0] = f2bf(v.x); o[1] = f2bf(v.y); o[2] = f2bf(v.z); o[3] = f2bf(v.w);
    *(u16x4*)(Xb + i) = o;
}

// ---------------------------------------------------------------------------
// Kernel 2: transpose+cast W[k][n] fp32 -> Wt[n][k] bf16  (z selects q/k/v)
// ---------------------------------------------------------------------------
__global__ __launch_bounds__(256) void cast_wt_kernel(
    const float* __restrict__ Wq, const float* __restrict__ Wk,
    const float* __restrict__ Wv, unsigned short* __restrict__ Wt)
{
    __shared__ float tile[64][65];
    int z = blockIdx.z;
    const float* W = (z == 0) ? Wq : ((z == 1) ? Wk : Wv);
    unsigned short* out = Wt + (size_t)z * HID * HID;
    int n0 = blockIdx.x * 64, k0 = blockIdx.y * 64;
    int tx = threadIdx.x & 63, ty0 = threadIdx.x >> 6;
#pragma unroll
    for (int i = 0; i < 16; i++) {
        int ty = ty0 * 16 + i;
        tile[ty][tx] = W[(size_t)(k0 + ty) * HID + n0 + tx];
    }
    __syncthreads();
#pragma unroll
    for (int i = 0; i < 16; i++) {
        int ty = ty0 * 16 + i;
        out[(size_t)(n0 + ty) * HID + k0 + tx] = f2bf(tile[tx][ty]);
    }
}

// ---------------------------------------------------------------------------
// Kernel 3: QKV GEMM, 128x128 tile, BK=32, global_load_lds staging,
// 4 waves each 64x64 (4x4 frags of 16x16x32 MFMA). Bias + table-RoPE epilogue.
// (unchanged this round)
// ---------------------------------------------------------------------------
#define BM 128
#define BN 128
#define BKQ 32

__global__ __launch_bounds__(256) void qkv_gemm_kernel(
    const unsigned short* __restrict__ Xb, const unsigned short* __restrict__ Wt,
    const float* __restrict__ bq, const float* __restrict__ bk,
    const float* __restrict__ bv,
    const float* __restrict__ cosT, const float* __restrict__ sinT,
    float* out,
    unsigned short* __restrict__ Qb, unsigned short* __restrict__ Kb,
    unsigned short* __restrict__ Vb)
{
    __shared__ unsigned short As[BM * BKQ];   // row-major [128][32], unpadded
    __shared__ unsigned short Bs[BN * BKQ];   // (global_load_lds layout rule)

    const size_t Q_OFF = (size_t)B_ * S_ * HID;
    const size_t K_OFF = 2 * Q_OFF;

    int z = blockIdx.z;
    const unsigned short* W = Wt + (size_t)z * HID * HID;
    const float* bias = (z == 0) ? bq : ((z == 1) ? bk : bv);

    int n0 = blockIdx.x * BN, m0 = blockIdx.y * BM;
    int tid = threadIdx.x;
    int wave = tid >> 6, lane = tid & 63;
    int quad = lane >> 4, l15 = lane & 15;
    int wm = (wave >> 1) * 64;
    int wn = (wave & 1) * 64;

    const unsigned short* Ag = Xb + (size_t)m0 * HID;
    const unsigned short* Bg = W  + (size_t)n0 * HID;

    int e0 = tid, e1 = 256 + tid;
    int r0 = e0 >> 2, c0 = (e0 & 3) * 8;
    int r1 = e1 >> 2, c1 = (e1 & 3) * 8;

    f32x4 acc[4][4] = {};

    for (int k0 = 0; k0 < HID; k0 += BKQ) {
        async16(Ag + (size_t)r0 * HID + k0 + c0, &As[e0 * 8]);
        async16(Ag + (size_t)r1 * HID + k0 + c1, &As[e1 * 8]);
        async16(Bg + (size_t)r0 * HID + k0 + c0, &Bs[e0 * 8]);
        async16(Bg + (size_t)r1 * HID + k0 + c1, &Bs[e1 * 8]);
        __syncthreads();

        bf16x8 af[4], bf[4];
#pragma unroll
        for (int t = 0; t < 4; t++)
            af[t] = *(const bf16x8*)&As[(wm + t * 16 + l15) * BKQ + quad * 8];
#pragma unroll
        for (int t = 0; t < 4; t++)
            bf[t] = *(const bf16x8*)&Bs[(wn + t * 16 + l15) * BKQ + quad * 8];
#pragma unroll
        for (int rt = 0; rt < 4; rt++)
#pragma unroll
            for (int ct = 0; ct < 4; ct++)
                acc[rt][ct] = __builtin_amdgcn_mfma_f32_16x16x32_bf16(
                    af[rt], bf[ct], acc[rt][ct], 0, 0, 0);
        __syncthreads();
    }

    // epilogue: C/D layout col = l15, row = quad*4 + r
#pragma unroll
    for (int ct = 0; ct < 4; ct++) {
        int n = n0 + wn + ct * 16 + l15;
        float bval = bias[n];
        int h = n >> 6, d = n & 63;
#pragma unroll
        for (int rt = 0; rt < 4; rt++) {
#pragma unroll
            for (int r = 0; r < 4; r++) {
                int m = m0 + wm + rt * 16 + quad * 4 + r;
                int b = m >> 11, s = m & (S_ - 1);
                float y = acc[rt][ct][r] + bval;
                size_t o = ((size_t)(b * H_ + h) * S_ + s) * D_ + d;
                if (z < 2) {
                    float c  = cosT[s * 64 + d];
                    float sn = sinT[s * 64 + d];
                    float p = __shfl_xor(y, 1);
                    float yr = ((d & 1) == 0) ? (y * c - p * sn) : (y * c + p * sn);
                    if (z == 0) { out[Q_OFF + o] = yr; Qb[o] = f2bf(yr); }
                    else        { out[K_OFF + o] = yr; Kb[o] = f2bf(yr); }
                } else {
                    Vb[o] = f2bf(y);
                }
            }
        }
    }
}

// ---------------------------------------------------------------------------
// Kernel 3b: transpose V: Vb[bh][s][d] -> Vt[bh][d][s]
// ---------------------------------------------------------------------------
__global__ __launch_bounds__(256) void transpose_v_kernel(
    const unsigned short* __restrict__ Vb, unsigned short* __restrict__ Vt)
{
    __shared__ unsigned short t[64][72];
    int bh = blockIdx.y;
    int s0 = blockIdx.x * 64;
    const unsigned short* src = Vb + ((size_t)bh * S_ + s0) * D_;
    unsigned short* dst = Vt + (size_t)bh * D_ * S_;
    int tid = threadIdx.x;
#pragma unroll
    for (int i = 0; i < 2; i++) {
        int e = i * 256 + tid;
        int row = e >> 3, c = (e & 7) * 8;
        u16x8 v = *(const u16x8*)(src + (size_t)row * D_ + c);
#pragma unroll
        for (int j = 0; j < 8; j++) t[row][c + j] = v[j];
    }
    __syncthreads();
#pragma unroll
    for (int i = 0; i < 2; i++) {
        int e = i * 256 + tid;
        int d = e >> 3, sc = (e & 7) * 8;
        u16x8 v;
#pragma unroll
        for (int j = 0; j < 8; j++) v[j] = t[sc + j][d];
        *(u16x8*)(dst + (size_t)d * S_ + s0 + sc) = v;
    }
}

// ---------------------------------------------------------------------------
// Kernel 4: flash attention. K/V double-buffered in padded LDS (TR=72),
// ONE barrier per kv-tile. P^T in registers via cvt_pk + permlane butterfly.
// psum from ones-row MFMA; V-frags roll-prefetched; mask reg-prefetched.
// ---------------------------------------------------------------------------
#define TR 72          // padded tile row, u16

__global__ __launch_bounds__(256, 4) void attn_kernel(
    const unsigned short* __restrict__ Qb, const unsigned short* __restrict__ Kb,
    const unsigned short* __restrict__ Vt, const float* __restrict__ mask,
    float* __restrict__ out)
{
    __shared__ union {
        struct {
            unsigned short Ks[2][64 * TR];     // 18432 B
            unsigned short Vs[2][64 * TR];     // 18432 B
        } s;                                    // 36864 B
        float oT[4][2][16][68];                 // 34816 B (epilogue)
    } u;

    int h  = blockIdx.x;
    int qt = blockIdx.y;
    int b  = blockIdx.z;
    int tid = threadIdx.x;
    int wave = tid >> 6, lane = tid & 63;
    int quad = lane >> 4, l15 = lane & 15;

    size_t bh = (size_t)(b * H_ + h);
    const unsigned short* Qp = Qb + bh * S_ * D_;
    const unsigned short* Kp = Kb + bh * S_ * D_;
    const unsigned short* Vp = Vt + bh * D_ * S_;
    const float* mp = mask + (size_t)b * S_;

    // Q B-frags (n=q, k=d), held in registers for the whole loop
    bf16x8 qb[2][2];
#pragma unroll
    for (int qg = 0; qg < 2; qg++)
#pragma unroll
        for (int hf = 0; hf < 2; hf++) {
            int qrow = qt * 128 + qg * 64 + wave * 16 + l15;
            qb[qg][hf] = *(const bf16x8*)(Qp + (size_t)qrow * D_ + hf * 32 + quad * 8);
        }

    f32x4 o[2][4] = {};
    f32x4 acc1[2] = {};            // psum accumulator (ones-row MFMA)
    const float C2    = 0.03125f * 1.44269504f;   // (1/sqrt(1024)) * log2(e)
    const float LOG2E = 1.44269504f;

    // ones A-fragment: A[0][k]=1 for all k, rows 1..15 = 0.
    // (lane layout: row = l15, k = quad*8 + j)
    bf16x8 ones_af;
    {
        short o1 = (l15 == 0) ? (short)0x3F80 : (short)0;
#pragma unroll
        for (int j = 0; j < 8; j++) ones_af[j] = o1;
    }

    // staging granules: rows 0..31 (e=tid) and 32..63 (e=tid+256); same col
    int sr0 = tid >> 3, sg0 = (tid & 7) * 8;
    int sr1 = sr0 + 32;

    // prologue: load tile 0 into regs (K, V, mask)
    u16x8 kr0 = *(const u16x8*)(Kp + (size_t)sr0 * D_ + sg0);
    u16x8 kr1 = *(const u16x8*)(Kp + (size_t)sr1 * D_ + sg0);
    u16x8 vr0 = *(const u16x8*)(Vp + (size_t)sr0 * S_ + sg0);
    u16x8 vr1 = *(const u16x8*)(Vp + (size_t)sr1 * S_ + sg0);
    f32x4 mk[4];
#pragma unroll
    for (int mt = 0; mt < 4; mt++)
        mk[mt] = *(const f32x4*)(mp + mt * 16 + quad * 4);

    int cur = 0;
    for (int kv0 = 0; kv0 < S_; kv0 += 64) {
        // stage current tile into buf[cur] (vmcnt drain happens here)
        *(u16x8*)&u.s.Ks[cur][sr0 * TR + sg0] = kr0;
        *(u16x8*)&u.s.Ks[cur][sr1 * TR + sg0] = kr1;
        *(u16x8*)&u.s.Vs[cur][sr0 * TR + sg0] = vr0;
        *(u16x8*)&u.s.Vs[cur][sr1 * TR + sg0] = vr1;
        __syncthreads();

        // issue next tile's global loads (drain overlaps compute below)
        int kvn = (kv0 + 64 < S_) ? kv0 + 64 : 0;
        kr0 = *(const u16x8*)(Kp + (size_t)(kvn + sr0) * D_ + sg0);
        kr1 = *(const u16x8*)(Kp + (size_t)(kvn + sr1) * D_ + sg0);
        vr0 = *(const u16x8*)(Vp + (size_t)sr0 * S_ + kvn + sg0);
        vr1 = *(const u16x8*)(Vp + (size_t)sr1 * S_ + kvn + sg0);
        f32x4 mkn[4];
#pragma unroll
        for (int mt = 0; mt < 4; mt++)
            mkn[mt] = *(const f32x4*)(mp + kvn + mt * 16 + quad * 4);

        const unsigned short* Ksc = u.s.Ks[cur];
        const unsigned short* Vsc = u.s.Vs[cur];

        // S^T: A = K rows (m=kv), B = Q (n=q); K-frags shared across q-groups
        f32x4 sa[2][4] = {};
        __builtin_amdgcn_s_setprio(1);
#pragma unroll
        for (int mt = 0; mt < 4; mt++) {
            bf16x8 kf0 = *(const bf16x8*)&Ksc[(mt * 16 + l15) * TR + quad * 8];
            bf16x8 kf1 = *(const bf16x8*)&Ksc[(mt * 16 + l15) * TR + 32 + quad * 8];
#pragma unroll
            for (int qg = 0; qg < 2; qg++) {
                sa[qg][mt] = __builtin_amdgcn_mfma_f32_16x16x32_bf16(kf0, qb[qg][0], sa[qg][mt], 0, 0, 0);
                sa[qg][mt] = __builtin_amdgcn_mfma_f32_16x16x32_bf16(kf1, qb[qg][1], sa[qg][mt], 0, 0, 0);
            }
        }
        __builtin_amdgcn_s_setprio(0);

        // early V-frags for ct=0: issue now, latency hides under softmax
        bf16x8 vf0 = *(const bf16x8*)&Vsc[l15 * TR + quad * 8];
        bf16x8 vf1 = *(const bf16x8*)&Vsc[l15 * TR + 32 + quad * 8];

        // p = exp2(s*C2 + mask*log2e); pack pairs to bf16 in-register
        unsigned pw[2][4][2];
#pragma unroll
        for (int mt = 0; mt < 4; mt++) {
#pragma unroll
            for (int qg = 0; qg < 2; qg++) {
                f32x4 pv;
#pragma unroll
                for (int r = 0; r < 4; r++)
                    pv[r] = fast_exp2(sa[qg][mt][r] * C2 + mk[mt][r] * LOG2E);
                asm("v_cvt_pk_bf16_f32 %0, %1, %2"
                    : "=v"(pw[qg][mt][0]) : "v"(pv[0]), "v"(pv[1]));
                asm("v_cvt_pk_bf16_f32 %0, %1, %2"
                    : "=v"(pw[qg][mt][1]) : "v"(pv[2]), "v"(pv[3]));
            }
        }
        // roll prefetched mask into current regs
#pragma unroll
        for (int mt = 0; mt < 4; mt++) mk[mt] = mkn[mt];

        // quad butterfly: pw[qg][mt][t] (lane qs holds kv=mt*16+qs*4+2t,+1)
        // -> pb[qg][hf] word t' = P^T[q=l15][kv=hf*32+quad*8+2t',+1]
        bf16x8 pb[2][2];
#pragma unroll
        for (int qg = 0; qg < 2; qg++)
#pragma unroll
            for (int hf = 0; hf < 2; hf++) {
                union { unsigned w[4]; bf16x8 v; } pbu;
#pragma unroll
                for (int t = 0; t < 2; t++) {
                    unsigned A = pw[qg][2 * hf + 0][t];
                    unsigned B = pw[qg][2 * hf + 1][t];
                    u32x2 r1 = __builtin_amdgcn_permlane32_swap(A, B, false, false);
                    u32x2 r2 = __builtin_amdgcn_permlane16_swap(r1[0], r1[1], false, false);
                    pbu.w[t]     = r2[0];
                    pbu.w[2 + t] = r2[1];
                }
                pb[qg][hf] = pbu.v;
            }

        // PV: A = V^T rows (m=d), B = P^T in registers; rolling V prefetch
        __builtin_amdgcn_s_setprio(1);
#pragma unroll
        for (int ct = 0; ct < 4; ct++) {
            bf16x8 nf0, nf1;
            if (ct < 3) {
                nf0 = *(const bf16x8*)&Vsc[((ct + 1) * 16 + l15) * TR + quad * 8];
                nf1 = *(const bf16x8*)&Vsc[((ct + 1) * 16 + l15) * TR + 32 + quad * 8];
            }
#pragma unroll
            for (int qg = 0; qg < 2; qg++) {
                o[qg][ct] = __builtin_amdgcn_mfma_f32_16x16x32_bf16(vf0, pb[qg][0], o[qg][ct], 0, 0, 0);
                o[qg][ct] = __builtin_amdgcn_mfma_f32_16x16x32_bf16(vf1, pb[qg][1], o[qg][ct], 0, 0, 0);
            }
            if (ct < 3) { vf0 = nf0; vf1 = nf1; }
        }
        // psum rows: D[0][q] = sum_k P[k][q], accumulated across tiles
#pragma unroll
        for (int qg = 0; qg < 2; qg++) {
            acc1[qg] = __builtin_amdgcn_mfma_f32_16x16x32_bf16(ones_af, pb[qg][0], acc1[qg], 0, 0, 0);
            acc1[qg] = __builtin_amdgcn_mfma_f32_16x16x32_bf16(ones_af, pb[qg][1], acc1[qg], 0, 0, 0);
        }
        __builtin_amdgcn_s_setprio(0);

        cur ^= 1;
    }
    __syncthreads();   // protect union reuse (oT overlaps Ks/Vs)

    // psum lives in row 0 (quad=0, reg 0): lane q (0..15) holds sum for q.
    // Broadcast to all lanes that handle q = l15.
    float psum[2];
#pragma unroll
    for (int qg = 0; qg < 2; qg++)
        psum[qg] = __shfl(acc1[qg][0], l15);

    // epilogue: normalize, transpose via LDS, coalesced store
#pragma unroll
    for (int qg = 0; qg < 2; qg++) {
        float inv = 1.0f / psum[qg];
#pragma unroll
        for (int ct = 0; ct < 4; ct++) {
            float4 vv;
            vv.x = o[qg][ct][0] * inv; vv.y = o[qg][ct][1] * inv;
            vv.z = o[qg][ct][2] * inv; vv.w = o[qg][ct][3] * inv;
            *(float4*)&u.oT[wave][qg][l15][ct * 16 + quad * 4] = vv;
        }
    }
    __builtin_amdgcn_wave_barrier();
    {
        int qq = lane >> 2, d0 = (lane & 3) * 16;
#pragma unroll
        for (int qg = 0; qg < 2; qg++) {
            int s_abs = qt * 128 + qg * 64 + wave * 16 + qq;
            float* dst = out + ((size_t)b * S_ + s_abs) * (H_ * D_) + h * D_ + d0;
#pragma unroll
            for (int j = 0; j < 4; j++) {
                float4 vj = *(float4*)&u.oT[wave][qg][qq][d0 + j * 4];
                *(float4*)(dst + j * 4) = vj;
            }
        }
    }
}

// ---------------------------------------------------------------------------
extern "C" void kernel_launch(void* const* d_in, const int* in_sizes, int n_in,
                              void* d_out, int out_size, void* d_ws, size_t ws_size,
                              hipStream_t stream)
{
    const float* X    = (const float*)d_in[0];
    const float* Wq   = (const float*)d_in[1];
    const float* bq   = (const float*)d_in[2];
    const float* Wk   = (const float*)d_in[3];
    const float* bk   = (const float*)d_in[4];
    const float* Wv   = (const float*)d_in[5];
    const float* bv   = (const float*)d_in[6];
    const float* mask = (const float*)d_in[7];

    char* ws = (char*)d_ws;
    unsigned short* Xb = (unsigned short*)(ws);                      // 16 MB (reused as Vt)
    unsigned short* Wt = (unsigned short*)(ws + 16777216);           //  6 MB
    unsigned short* Qb = (unsigned short*)(ws + 23068672);           // 16 MB
    unsigned short* Kb = (unsigned short*)(ws + 39845888);           // 16 MB
    unsigned short* Vb = (unsigned short*)(ws + 56623104);           // 16 MB
    unsigned short* Vt = Xb;   // Xb dead after qkv_gemm; reuse for V^T

    float* tab = (float*)d_out;   // RoPE tables in ctx region (overwritten by attn)

    rope_table_kernel<<<dim3(131072 / 256), 256, 0, stream>>>(tab);
    cast_x_kernel<<<dim3(M_ * HID / 4 / 256), 256, 0, stream>>>(X, Xb);
    cast_wt_kernel<<<dim3(16, 16, 3), 256, 0, stream>>>(Wq, Wk, Wv, Wt);
    qkv_gemm_kernel<<<dim3(HID / BN, M_ / BM, 3), 256, 0, stream>>>(
        Xb, Wt, bq, bk, bv, tab, tab + 131072, (float*)d_out, Qb, Kb, Vb);
    transpose_v_kernel<<<dim3(S_ / 64, B_ * H_), 256, 0, stream>>>(Vb, Vt);
    attn_kernel<<<dim3(H_, S_ / 128, B_), 256, 0, stream>>>(
        Qb, Kb, Vt, mask, (float*)d_out);
}

// Round 3
// 403.705 us; speedup vs baseline: 1.9906x; 1.9906x over previous
//
#include <hip/hip_runtime.h>

// ---------------------------------------------------------------------------
// MultiHeadsAttention: X[4,2048,1024] -> ctx[4,2048,1024], q[4,16,2048,64],
// k[4,16,2048,64] (q,k post-RoPE). fp32 in/out, bf16 MFMA internally.
// Round 11: R10's attn additions (mask dbuf + rolling V-frags + ones-MFMA)
// crossed the VGPR allocation cliff -> 1.3 GB/dispatch scratch spill traffic
// (FETCH 27MB->1.12GB, WRITE 37MB->1.35GB, 528us). REVERT attn to the
// measured-good R9 kernel (158us, VGPR=64, zero spill).
// This round's experiment: qkv_gemm T3 2-phase pipeline — double-buffered
// LDS (16->32KB), next K-tile's global_load_lds issued BEFORE computing the
// current tile, ONE __syncthreads per iteration (loads land under the
// ~500cy ds_read+MFMA phase instead of a cold vmcnt(0) drain).
// ---------------------------------------------------------------------------

#define B_  4
#define S_  2048
#define H_  16
#define D_  64
#define HID 1024
#define M_  (B_ * S_)          // 8192

typedef __attribute__((ext_vector_type(8))) short    bf16x8;
typedef __attribute__((ext_vector_type(4))) float    f32x4;
typedef __attribute__((ext_vector_type(4))) unsigned short u16x4;
typedef __attribute__((ext_vector_type(8))) unsigned short u16x8;
typedef __attribute__((ext_vector_type(2))) unsigned u32x2;

__device__ __forceinline__ unsigned short f2bf(float f) {
    union { float f; unsigned u; } v; v.f = f;
    unsigned r = v.u + 0x7fffu + ((v.u >> 16) & 1u);
    return (unsigned short)(r >> 16);
}

__device__ __forceinline__ void async16(const unsigned short* g, unsigned short* l) {
    __builtin_amdgcn_global_load_lds(
        (const __attribute__((address_space(1))) void*)g,
        (__attribute__((address_space(3))) void*)l, 16, 0, 0);
}

// ---------------------------------------------------------------------------
// Kernel 0: RoPE tables -> d_out ctx region (overwritten later by attn).
// ---------------------------------------------------------------------------
__global__ __launch_bounds__(256) void rope_table_kernel(float* __restrict__ tab)
{
    int i = blockIdx.x * 256 + threadIdx.x;     // 0 .. 131071
    int s = i >> 6, d = i & 63;
    const float NEG_LN1E4_32 = -0.28782313662425576f;  // -ln(10000)/32
    float freq = __expf(NEG_LN1E4_32 * (float)(d >> 1));
    float ang = (float)s * freq;
    tab[i]          = cosf(ang);
    tab[131072 + i] = sinf(ang);
}

// ---------------------------------------------------------------------------
// Kernel 1: cast X fp32 -> bf16
// ---------------------------------------------------------------------------
__global__ __launch_bounds__(256) void cast_x_kernel(
    const float* __restrict__ X, unsigned short* __restrict__ Xb)
{
    int i = (blockIdx.x * 256 + threadIdx.x) * 4;
    float4 v = *(const float4*)(X + i);
    u16x4 o;
    o[0] = f2bf(v.x); o[1] = f2bf(v.y); o[2] = f2bf(v.z); o[3] = f2bf(v.w);
    *(u16x4*)(Xb + i) = o;
}

// ---------------------------------------------------------------------------
// Kernel 2: transpose+cast W[k][n] fp32 -> Wt[n][k] bf16  (z selects q/k/v)
// ---------------------------------------------------------------------------
__global__ __launch_bounds__(256) void cast_wt_kernel(
    const float* __restrict__ Wq, const float* __restrict__ Wk,
    const float* __restrict__ Wv, unsigned short* __restrict__ Wt)
{
    __shared__ float tile[64][65];
    int z = blockIdx.z;
    const float* W = (z == 0) ? Wq : ((z == 1) ? Wk : Wv);
    unsigned short* out = Wt + (size_t)z * HID * HID;
    int n0 = blockIdx.x * 64, k0 = blockIdx.y * 64;
    int tx = threadIdx.x & 63, ty0 = threadIdx.x >> 6;
#pragma unroll
    for (int i = 0; i < 16; i++) {
        int ty = ty0 * 16 + i;
        tile[ty][tx] = W[(size_t)(k0 + ty) * HID + n0 + tx];
    }
    __syncthreads();
#pragma unroll
    for (int i = 0; i < 16; i++) {
        int ty = ty0 * 16 + i;
        out[(size_t)(n0 + ty) * HID + k0 + tx] = f2bf(tile[tx][ty]);
    }
}

// ---------------------------------------------------------------------------
// Kernel 3: QKV GEMM, 128x128 tile, BK=32, global_load_lds staging,
// 4 waves each 64x64 (4x4 frags of 16x16x32 MFMA). Bias + table-RoPE epilogue.
// Round 11: T3 2-phase pipeline — LDS double-buffered, next tile's async
// loads issued pre-compute, one barrier/iter.
// ---------------------------------------------------------------------------
#define BM 128
#define BN 128
#define BKQ 32

__global__ __launch_bounds__(256) void qkv_gemm_kernel(
    const unsigned short* __restrict__ Xb, const unsigned short* __restrict__ Wt,
    const float* __restrict__ bq, const float* __restrict__ bk,
    const float* __restrict__ bv,
    const float* __restrict__ cosT, const float* __restrict__ sinT,
    float* out,
    unsigned short* __restrict__ Qb, unsigned short* __restrict__ Kb,
    unsigned short* __restrict__ Vb)
{
    __shared__ unsigned short As[2][BM * BKQ];   // 2 x 8 KB
    __shared__ unsigned short Bs[2][BN * BKQ];   // 2 x 8 KB

    const size_t Q_OFF = (size_t)B_ * S_ * HID;
    const size_t K_OFF = 2 * Q_OFF;

    int z = blockIdx.z;
    const unsigned short* W = Wt + (size_t)z * HID * HID;
    const float* bias = (z == 0) ? bq : ((z == 1) ? bk : bv);

    int n0 = blockIdx.x * BN, m0 = blockIdx.y * BM;
    int tid = threadIdx.x;
    int wave = tid >> 6, lane = tid & 63;
    int quad = lane >> 4, l15 = lane & 15;
    int wm = (wave >> 1) * 64;
    int wn = (wave & 1) * 64;

    const unsigned short* Ag = Xb + (size_t)m0 * HID;
    const unsigned short* Bg = W  + (size_t)n0 * HID;

    int e0 = tid, e1 = 256 + tid;
    int r0 = e0 >> 2, c0 = (e0 & 3) * 8;
    int r1 = e1 >> 2, c1 = (e1 & 3) * 8;

    f32x4 acc[4][4] = {};

    // prologue: stage K-tile 0 into buf 0, drain, barrier
    async16(Ag + (size_t)r0 * HID + c0, &As[0][e0 * 8]);
    async16(Ag + (size_t)r1 * HID + c1, &As[0][e1 * 8]);
    async16(Bg + (size_t)r0 * HID + c0, &Bs[0][e0 * 8]);
    async16(Bg + (size_t)r1 * HID + c1, &Bs[0][e1 * 8]);
    __syncthreads();

    int cur = 0;
    for (int k0 = 0; k0 < HID; k0 += BKQ) {
        // issue next tile's loads into buf[cur^1]; they land under compute
        int kn = k0 + BKQ;
        if (kn < HID) {
            async16(Ag + (size_t)r0 * HID + kn + c0, &As[cur ^ 1][e0 * 8]);
            async16(Ag + (size_t)r1 * HID + kn + c1, &As[cur ^ 1][e1 * 8]);
            async16(Bg + (size_t)r0 * HID + kn + c0, &Bs[cur ^ 1][e0 * 8]);
            async16(Bg + (size_t)r1 * HID + kn + c1, &Bs[cur ^ 1][e1 * 8]);
        }

        bf16x8 af[4], bf[4];
#pragma unroll
        for (int t = 0; t < 4; t++)
            af[t] = *(const bf16x8*)&As[cur][(wm + t * 16 + l15) * BKQ + quad * 8];
#pragma unroll
        for (int t = 0; t < 4; t++)
            bf[t] = *(const bf16x8*)&Bs[cur][(wn + t * 16 + l15) * BKQ + quad * 8];
#pragma unroll
        for (int rt = 0; rt < 4; rt++)
#pragma unroll
            for (int ct = 0; ct < 4; ct++)
                acc[rt][ct] = __builtin_amdgcn_mfma_f32_16x16x32_bf16(
                    af[rt], bf[ct], acc[rt][ct], 0, 0, 0);

        // one barrier/iter: per-wave vmcnt(0) drain (next tile landed) +
        // all waves done reading buf[cur] -> safe to overwrite next iter
        __syncthreads();
        cur ^= 1;
    }

    // epilogue: C/D layout col = l15, row = quad*4 + r
#pragma unroll
    for (int ct = 0; ct < 4; ct++) {
        int n = n0 + wn + ct * 16 + l15;
        float bval = bias[n];
        int h = n >> 6, d = n & 63;
#pragma unroll
        for (int rt = 0; rt < 4; rt++) {
#pragma unroll
            for (int r = 0; r < 4; r++) {
                int m = m0 + wm + rt * 16 + quad * 4 + r;
                int b = m >> 11, s = m & (S_ - 1);
                float y = acc[rt][ct][r] + bval;
                size_t o = ((size_t)(b * H_ + h) * S_ + s) * D_ + d;
                if (z < 2) {
                    float c  = cosT[s * 64 + d];
                    float sn = sinT[s * 64 + d];
                    float p = __shfl_xor(y, 1);
                    float yr = ((d & 1) == 0) ? (y * c - p * sn) : (y * c + p * sn);
                    if (z == 0) { out[Q_OFF + o] = yr; Qb[o] = f2bf(yr); }
                    else        { out[K_OFF + o] = yr; Kb[o] = f2bf(yr); }
                } else {
                    Vb[o] = f2bf(y);
                }
            }
        }
    }
}

// ---------------------------------------------------------------------------
// Kernel 3b: transpose V: Vb[bh][s][d] -> Vt[bh][d][s]
// ---------------------------------------------------------------------------
__global__ __launch_bounds__(256) void transpose_v_kernel(
    const unsigned short* __restrict__ Vb, unsigned short* __restrict__ Vt)
{
    __shared__ unsigned short t[64][72];
    int bh = blockIdx.y;
    int s0 = blockIdx.x * 64;
    const unsigned short* src = Vb + ((size_t)bh * S_ + s0) * D_;
    unsigned short* dst = Vt + (size_t)bh * D_ * S_;
    int tid = threadIdx.x;
#pragma unroll
    for (int i = 0; i < 2; i++) {
        int e = i * 256 + tid;
        int row = e >> 3, c = (e & 7) * 8;
        u16x8 v = *(const u16x8*)(src + (size_t)row * D_ + c);
#pragma unroll
        for (int j = 0; j < 8; j++) t[row][c + j] = v[j];
    }
    __syncthreads();
#pragma unroll
    for (int i = 0; i < 2; i++) {
        int e = i * 256 + tid;
        int d = e >> 3, sc = (e & 7) * 8;
        u16x8 v;
#pragma unroll
        for (int j = 0; j < 8; j++) v[j] = t[sc + j][d];
        *(u16x8*)(dst + (size_t)d * S_ + s0 + sc) = v;
    }
}

// ---------------------------------------------------------------------------
// Kernel 4: flash attention (R9 verbatim — measured 158us, VGPR=64, no
// spill). K/V double-buffered in padded LDS (TR=72), ONE barrier per
// kv-tile. P^T never touches LDS: cvt_pk + permlane butterfly.
// ---------------------------------------------------------------------------
#define TR 72          // padded tile row, u16

__global__ __launch_bounds__(256, 4) void attn_kernel(
    const unsigned short* __restrict__ Qb, const unsigned short* __restrict__ Kb,
    const unsigned short* __restrict__ Vt, const float* __restrict__ mask,
    float* __restrict__ out)
{
    __shared__ union {
        struct {
            unsigned short Ks[2][64 * TR];     // 18432 B
            unsigned short Vs[2][64 * TR];     // 18432 B
        } s;                                    // 36864 B
        float oT[4][2][16][68];                 // 34816 B (epilogue)
    } u;

    int h  = blockIdx.x;
    int qt = blockIdx.y;
    int b  = blockIdx.z;
    int tid = threadIdx.x;
    int wave = tid >> 6, lane = tid & 63;
    int quad = lane >> 4, l15 = lane & 15;

    size_t bh = (size_t)(b * H_ + h);
    const unsigned short* Qp = Qb + bh * S_ * D_;
    const unsigned short* Kp = Kb + bh * S_ * D_;
    const unsigned short* Vp = Vt + bh * D_ * S_;
    const float* mp = mask + (size_t)b * S_;

    // Q B-frags (n=q, k=d), held in registers for the whole loop
    bf16x8 qb[2][2];
#pragma unroll
    for (int qg = 0; qg < 2; qg++)
#pragma unroll
        for (int hf = 0; hf < 2; hf++) {
            int qrow = qt * 128 + qg * 64 + wave * 16 + l15;
            qb[qg][hf] = *(const bf16x8*)(Qp + (size_t)qrow * D_ + hf * 32 + quad * 8);
        }

    f32x4 o[2][4] = {};
    float psum[2] = {0.0f, 0.0f};
    const float C2    = 0.03125f * 1.44269504f;   // (1/sqrt(1024)) * log2(e)
    const float LOG2E = 1.44269504f;

    // staging granules: rows 0..31 (e=tid) and 32..63 (e=tid+256); same col
    int sr0 = tid >> 3, sg0 = (tid & 7) * 8;
    int sr1 = sr0 + 32;

    // prologue: load tile 0 into regs
    u16x8 kr0 = *(const u16x8*)(Kp + (size_t)sr0 * D_ + sg0);
    u16x8 kr1 = *(const u16x8*)(Kp + (size_t)sr1 * D_ + sg0);
    u16x8 vr0 = *(const u16x8*)(Vp + (size_t)sr0 * S_ + sg0);
    u16x8 vr1 = *(const u16x8*)(Vp + (size_t)sr1 * S_ + sg0);

    int cur = 0;
    for (int kv0 = 0; kv0 < S_; kv0 += 64) {
        // stage current tile into buf[cur] (vmcnt drain happens here)
        *(u16x8*)&u.s.Ks[cur][sr0 * TR + sg0] = kr0;
        *(u16x8*)&u.s.Ks[cur][sr1 * TR + sg0] = kr1;
        *(u16x8*)&u.s.Vs[cur][sr0 * TR + sg0] = vr0;
        *(u16x8*)&u.s.Vs[cur][sr1 * TR + sg0] = vr1;
        __syncthreads();

        // issue next tile's global loads (drain overlaps compute below)
        int kvn = (kv0 + 64 < S_) ? kv0 + 64 : 0;
        kr0 = *(const u16x8*)(Kp + (size_t)(kvn + sr0) * D_ + sg0);
        kr1 = *(const u16x8*)(Kp + (size_t)(kvn + sr1) * D_ + sg0);
        vr0 = *(const u16x8*)(Vp + (size_t)sr0 * S_ + kvn + sg0);
        vr1 = *(const u16x8*)(Vp + (size_t)sr1 * S_ + kvn + sg0);

        const unsigned short* Ksc = u.s.Ks[cur];
        const unsigned short* Vsc = u.s.Vs[cur];

        // S^T: A = K rows (m=kv), B = Q (n=q); K-frags shared across q-groups
        f32x4 sa[2][4] = {};
        __builtin_amdgcn_s_setprio(1);
#pragma unroll
        for (int mt = 0; mt < 4; mt++) {
            bf16x8 kf0 = *(const bf16x8*)&Ksc[(mt * 16 + l15) * TR + quad * 8];
            bf16x8 kf1 = *(const bf16x8*)&Ksc[(mt * 16 + l15) * TR + 32 + quad * 8];
#pragma unroll
            for (int qg = 0; qg < 2; qg++) {
                sa[qg][mt] = __builtin_amdgcn_mfma_f32_16x16x32_bf16(kf0, qb[qg][0], sa[qg][mt], 0, 0, 0);
                sa[qg][mt] = __builtin_amdgcn_mfma_f32_16x16x32_bf16(kf1, qb[qg][1], sa[qg][mt], 0, 0, 0);
            }
        }
        __builtin_amdgcn_s_setprio(0);

        // p = exp2(s*C2 + mask*log2e); pack pairs to bf16 in-register
        unsigned pw[2][4][2];
#pragma unroll
        for (int mt = 0; mt < 4; mt++) {
            f32x4 mkv = *(const f32x4*)(mp + kv0 + mt * 16 + quad * 4);
#pragma unroll
            for (int qg = 0; qg < 2; qg++) {
                f32x4 pv;
#pragma unroll
                for (int r = 0; r < 4; r++)
                    pv[r] = exp2f(sa[qg][mt][r] * C2 + mkv[r] * LOG2E);
                psum[qg] += (pv[0] + pv[1]) + (pv[2] + pv[3]);
                asm("v_cvt_pk_bf16_f32 %0, %1, %2"
                    : "=v"(pw[qg][mt][0]) : "v"(pv[0]), "v"(pv[1]));
                asm("v_cvt_pk_bf16_f32 %0, %1, %2"
                    : "=v"(pw[qg][mt][1]) : "v"(pv[2]), "v"(pv[3]));
            }
        }

        // quad butterfly: pw[qg][mt][t] (lane qs holds kv=mt*16+qs*4+2t,+1)
        // -> pb[qg][hf] word t' = P^T[q=l15][kv=hf*32+quad*8+2t',+1]
        bf16x8 pb[2][2];
#pragma unroll
        for (int qg = 0; qg < 2; qg++)
#pragma unroll
            for (int hf = 0; hf < 2; hf++) {
                union { unsigned w[4]; bf16x8 v; } pbu;
#pragma unroll
                for (int t = 0; t < 2; t++) {
                    unsigned A = pw[qg][2 * hf + 0][t];
                    unsigned B = pw[qg][2 * hf + 1][t];
                    u32x2 r1 = __builtin_amdgcn_permlane32_swap(A, B, false, false);
                    u32x2 r2 = __builtin_amdgcn_permlane16_swap(r1[0], r1[1], false, false);
                    pbu.w[t]     = r2[0];
                    pbu.w[2 + t] = r2[1];
                }
                pb[qg][hf] = pbu.v;
            }

        // PV: A = V^T rows (m=d), B = P^T in registers; V-frags shared
        __builtin_amdgcn_s_setprio(1);
#pragma unroll
        for (int ct = 0; ct < 4; ct++) {
            bf16x8 vf0 = *(const bf16x8*)&Vsc[(ct * 16 + l15) * TR + quad * 8];
            bf16x8 vf1 = *(const bf16x8*)&Vsc[(ct * 16 + l15) * TR + 32 + quad * 8];
#pragma unroll
            for (int qg = 0; qg < 2; qg++) {
                o[qg][ct] = __builtin_amdgcn_mfma_f32_16x16x32_bf16(vf0, pb[qg][0], o[qg][ct], 0, 0, 0);
                o[qg][ct] = __builtin_amdgcn_mfma_f32_16x16x32_bf16(vf1, pb[qg][1], o[qg][ct], 0, 0, 0);
            }
        }
        __builtin_amdgcn_s_setprio(0);

        cur ^= 1;
    }
    __syncthreads();   // protect union reuse (oT overlaps Ks/Vs)

    // l reduction over the 4 quads (kv partitions), once
#pragma unroll
    for (int qg = 0; qg < 2; qg++) {
        psum[qg] += __shfl_xor(psum[qg], 16);
        psum[qg] += __shfl_xor(psum[qg], 32);
    }

    // epilogue: normalize, transpose via LDS, coalesced store
#pragma unroll
    for (int qg = 0; qg < 2; qg++) {
        float inv = 1.0f / psum[qg];
#pragma unroll
        for (int ct = 0; ct < 4; ct++) {
            float4 vv;
            vv.x = o[qg][ct][0] * inv; vv.y = o[qg][ct][1] * inv;
            vv.z = o[qg][ct][2] * inv; vv.w = o[qg][ct][3] * inv;
            *(float4*)&u.oT[wave][qg][l15][ct * 16 + quad * 4] = vv;
        }
    }
    __builtin_amdgcn_wave_barrier();
    {
        int qq = lane >> 2, d0 = (lane & 3) * 16;
#pragma unroll
        for (int qg = 0; qg < 2; qg++) {
            int s_abs = qt * 128 + qg * 64 + wave * 16 + qq;
            float* dst = out + ((size_t)b * S_ + s_abs) * (H_ * D_) + h * D_ + d0;
#pragma unroll
            for (int j = 0; j < 4; j++) {
                float4 vj = *(float4*)&u.oT[wave][qg][qq][d0 + j * 4];
                *(float4*)(dst + j * 4) = vj;
            }
        }
    }
}

// ---------------------------------------------------------------------------
extern "C" void kernel_launch(void* const* d_in, const int* in_sizes, int n_in,
                              void* d_out, int out_size, void* d_ws, size_t ws_size,
                              hipStream_t stream)
{
    const float* X    = (const float*)d_in[0];
    const float* Wq   = (const float*)d_in[1];
    const float* bq   = (const float*)d_in[2];
    const float* Wk   = (const float*)d_in[3];
    const float* bk   = (const float*)d_in[4];
    const float* Wv   = (const float*)d_in[5];
    const float* bv   = (const float*)d_in[6];
    const float* mask = (const float*)d_in[7];

    char* ws = (char*)d_ws;
    unsigned short* Xb = (unsigned short*)(ws);                      // 16 MB (reused as Vt)
    unsigned short* Wt = (unsigned short*)(ws + 16777216);           //  6 MB
    unsigned short* Qb = (unsigned short*)(ws + 23068672);           // 16 MB
    unsigned short* Kb = (unsigned short*)(ws + 39845888);           // 16 MB
    unsigned short* Vb = (unsigned short*)(ws + 56623104);           // 16 MB
    unsigned short* Vt = Xb;   // Xb dead after qkv_gemm; reuse for V^T

    float* tab = (float*)d_out;   // RoPE tables in ctx region (overwritten by attn)

    rope_table_kernel<<<dim3(131072 / 256), 256, 0, stream>>>(tab);
    cast_x_kernel<<<dim3(M_ * HID / 4 / 256), 256, 0, stream>>>(X, Xb);
    cast_wt_kernel<<<dim3(16, 16, 3), 256, 0, stream>>>(Wq, Wk, Wv, Wt);
    qkv_gemm_kernel<<<dim3(HID / BN, M_ / BM, 3), 256, 0, stream>>>(
        Xb, Wt, bq, bk, bv, tab, tab + 131072, (float*)d_out, Qb, Kb, Vb);
    transpose_v_kernel<<<dim3(S_ / 64, B_ * H_), 256, 0, stream>>>(Vb, Vt);
    attn_kernel<<<dim3(H_, S_ / 128, B_), 256, 0, stream>>>(
        Qb, Kb, Vt, mask, (float*)d_out);
}

// Round 4
// 367.966 us; speedup vs baseline: 2.1839x; 1.0971x over previous
//
#include <hip/hip_runtime.h>

// ---------------------------------------------------------------------------
// MultiHeadsAttention: X[4,2048,1024] -> ctx[4,2048,1024], q[4,16,2048,64],
// k[4,16,2048,64] (q,k post-RoPE). fp32 in/out, bf16 MFMA internally.
// Round 12: (1) qkv reverted to R9 single-buffer (R11 dbuf was +4.7us,
// replicating m99/m100 "explicit dbuf neutral in 2-barrier structures").
// (2) attn: exp2f -> raw v_exp_f32 asm, the ONLY attn change (R10 showed
// this is safe; the spill came from its register-hungry companions).
// OCML exp2f expands to ~8-12 guarded ops; range here is |x|<~10 so the
// single HW instruction is exact enough. Removes ~500cy/wave-iter of VALU
// issue (~15-20% of the 61% VALUBusy).
// ---------------------------------------------------------------------------

#define B_  4
#define S_  2048
#define H_  16
#define D_  64
#define HID 1024
#define M_  (B_ * S_)          // 8192

typedef __attribute__((ext_vector_type(8))) short    bf16x8;
typedef __attribute__((ext_vector_type(4))) float    f32x4;
typedef __attribute__((ext_vector_type(4))) unsigned short u16x4;
typedef __attribute__((ext_vector_type(8))) unsigned short u16x8;
typedef __attribute__((ext_vector_type(2))) unsigned u32x2;

__device__ __forceinline__ unsigned short f2bf(float f) {
    union { float f; unsigned u; } v; v.f = f;
    unsigned r = v.u + 0x7fffu + ((v.u >> 16) & 1u);
    return (unsigned short)(r >> 16);
}

__device__ __forceinline__ void async16(const unsigned short* g, unsigned short* l) {
    __builtin_amdgcn_global_load_lds(
        (const __attribute__((address_space(1))) void*)g,
        (__attribute__((address_space(3))) void*)l, 16, 0, 0);
}

__device__ __forceinline__ float fast_exp2(float x) {
    float r;
    asm("v_exp_f32 %0, %1" : "=v"(r) : "v"(x));
    return r;
}

// ---------------------------------------------------------------------------
// Kernel 0: RoPE tables -> d_out ctx region (overwritten later by attn).
// ---------------------------------------------------------------------------
__global__ __launch_bounds__(256) void rope_table_kernel(float* __restrict__ tab)
{
    int i = blockIdx.x * 256 + threadIdx.x;     // 0 .. 131071
    int s = i >> 6, d = i & 63;
    const float NEG_LN1E4_32 = -0.28782313662425576f;  // -ln(10000)/32
    float freq = __expf(NEG_LN1E4_32 * (float)(d >> 1));
    float ang = (float)s * freq;
    tab[i]          = cosf(ang);
    tab[131072 + i] = sinf(ang);
}

// ---------------------------------------------------------------------------
// Kernel 1: cast X fp32 -> bf16
// ---------------------------------------------------------------------------
__global__ __launch_bounds__(256) void cast_x_kernel(
    const float* __restrict__ X, unsigned short* __restrict__ Xb)
{
    int i = (blockIdx.x * 256 + threadIdx.x) * 4;
    float4 v = *(const float4*)(X + i);
    u16x4 o;
    o[0] = f2bf(v.x); o[1] = f2bf(v.y); o[2] = f2bf(v.z); o[3] = f2bf(v.w);
    *(u16x4*)(Xb + i) = o;
}

// ---------------------------------------------------------------------------
// Kernel 2: transpose+cast W[k][n] fp32 -> Wt[n][k] bf16  (z selects q/k/v)
// ---------------------------------------------------------------------------
__global__ __launch_bounds__(256) void cast_wt_kernel(
    const float* __restrict__ Wq, const float* __restrict__ Wk,
    const float* __restrict__ Wv, unsigned short* __restrict__ Wt)
{
    __shared__ float tile[64][65];
    int z = blockIdx.z;
    const float* W = (z == 0) ? Wq : ((z == 1) ? Wk : Wv);
    unsigned short* out = Wt + (size_t)z * HID * HID;
    int n0 = blockIdx.x * 64, k0 = blockIdx.y * 64;
    int tx = threadIdx.x & 63, ty0 = threadIdx.x >> 6;
#pragma unroll
    for (int i = 0; i < 16; i++) {
        int ty = ty0 * 16 + i;
        tile[ty][tx] = W[(size_t)(k0 + ty) * HID + n0 + tx];
    }
    __syncthreads();
#pragma unroll
    for (int i = 0; i < 16; i++) {
        int ty = ty0 * 16 + i;
        out[(size_t)(n0 + ty) * HID + k0 + tx] = f2bf(tile[tx][ty]);
    }
}

// ---------------------------------------------------------------------------
// Kernel 3: QKV GEMM, 128x128 tile, BK=32, global_load_lds staging,
// 4 waves each 64x64 (4x4 frags of 16x16x32 MFMA). Bias + table-RoPE epilogue.
// (R9 single-buffer structure — measured better than R11 dbuf)
// ---------------------------------------------------------------------------
#define BM 128
#define BN 128
#define BKQ 32

__global__ __launch_bounds__(256) void qkv_gemm_kernel(
    const unsigned short* __restrict__ Xb, const unsigned short* __restrict__ Wt,
    const float* __restrict__ bq, const float* __restrict__ bk,
    const float* __restrict__ bv,
    const float* __restrict__ cosT, const float* __restrict__ sinT,
    float* out,
    unsigned short* __restrict__ Qb, unsigned short* __restrict__ Kb,
    unsigned short* __restrict__ Vb)
{
    __shared__ unsigned short As[BM * BKQ];   // row-major [128][32], unpadded
    __shared__ unsigned short Bs[BN * BKQ];   // (global_load_lds layout rule)

    const size_t Q_OFF = (size_t)B_ * S_ * HID;
    const size_t K_OFF = 2 * Q_OFF;

    int z = blockIdx.z;
    const unsigned short* W = Wt + (size_t)z * HID * HID;
    const float* bias = (z == 0) ? bq : ((z == 1) ? bk : bv);

    int n0 = blockIdx.x * BN, m0 = blockIdx.y * BM;
    int tid = threadIdx.x;
    int wave = tid >> 6, lane = tid & 63;
    int quad = lane >> 4, l15 = lane & 15;
    int wm = (wave >> 1) * 64;
    int wn = (wave & 1) * 64;

    const unsigned short* Ag = Xb + (size_t)m0 * HID;
    const unsigned short* Bg = W  + (size_t)n0 * HID;

    int e0 = tid, e1 = 256 + tid;
    int r0 = e0 >> 2, c0 = (e0 & 3) * 8;
    int r1 = e1 >> 2, c1 = (e1 & 3) * 8;

    f32x4 acc[4][4] = {};

    for (int k0 = 0; k0 < HID; k0 += BKQ) {
        async16(Ag + (size_t)r0 * HID + k0 + c0, &As[e0 * 8]);
        async16(Ag + (size_t)r1 * HID + k0 + c1, &As[e1 * 8]);
        async16(Bg + (size_t)r0 * HID + k0 + c0, &Bs[e0 * 8]);
        async16(Bg + (size_t)r1 * HID + k0 + c1, &Bs[e1 * 8]);
        __syncthreads();

        bf16x8 af[4], bf[4];
#pragma unroll
        for (int t = 0; t < 4; t++)
            af[t] = *(const bf16x8*)&As[(wm + t * 16 + l15) * BKQ + quad * 8];
#pragma unroll
        for (int t = 0; t < 4; t++)
            bf[t] = *(const bf16x8*)&Bs[(wn + t * 16 + l15) * BKQ + quad * 8];
#pragma unroll
        for (int rt = 0; rt < 4; rt++)
#pragma unroll
            for (int ct = 0; ct < 4; ct++)
                acc[rt][ct] = __builtin_amdgcn_mfma_f32_16x16x32_bf16(
                    af[rt], bf[ct], acc[rt][ct], 0, 0, 0);
        __syncthreads();
    }

    // epilogue: C/D layout col = l15, row = quad*4 + r
#pragma unroll
    for (int ct = 0; ct < 4; ct++) {
        int n = n0 + wn + ct * 16 + l15;
        float bval = bias[n];
        int h = n >> 6, d = n & 63;
#pragma unroll
        for (int rt = 0; rt < 4; rt++) {
#pragma unroll
            for (int r = 0; r < 4; r++) {
                int m = m0 + wm + rt * 16 + quad * 4 + r;
                int b = m >> 11, s = m & (S_ - 1);
                float y = acc[rt][ct][r] + bval;
                size_t o = ((size_t)(b * H_ + h) * S_ + s) * D_ + d;
                if (z < 2) {
                    float c  = cosT[s * 64 + d];
                    float sn = sinT[s * 64 + d];
                    float p = __shfl_xor(y, 1);
                    float yr = ((d & 1) == 0) ? (y * c - p * sn) : (y * c + p * sn);
                    if (z == 0) { out[Q_OFF + o] = yr; Qb[o] = f2bf(yr); }
                    else        { out[K_OFF + o] = yr; Kb[o] = f2bf(yr); }
                } else {
                    Vb[o] = f2bf(y);
                }
            }
        }
    }
}

// ---------------------------------------------------------------------------
// Kernel 3b: transpose V: Vb[bh][s][d] -> Vt[bh][d][s]
// ---------------------------------------------------------------------------
__global__ __launch_bounds__(256) void transpose_v_kernel(
    const unsigned short* __restrict__ Vb, unsigned short* __restrict__ Vt)
{
    __shared__ unsigned short t[64][72];
    int bh = blockIdx.y;
    int s0 = blockIdx.x * 64;
    const unsigned short* src = Vb + ((size_t)bh * S_ + s0) * D_;
    unsigned short* dst = Vt + (size_t)bh * D_ * S_;
    int tid = threadIdx.x;
#pragma unroll
    for (int i = 0; i < 2; i++) {
        int e = i * 256 + tid;
        int row = e >> 3, c = (e & 7) * 8;
        u16x8 v = *(const u16x8*)(src + (size_t)row * D_ + c);
#pragma unroll
        for (int j = 0; j < 8; j++) t[row][c + j] = v[j];
    }
    __syncthreads();
#pragma unroll
    for (int i = 0; i < 2; i++) {
        int e = i * 256 + tid;
        int d = e >> 3, sc = (e & 7) * 8;
        u16x8 v;
#pragma unroll
        for (int j = 0; j < 8; j++) v[j] = t[sc + j][d];
        *(u16x8*)(dst + (size_t)d * S_ + s0 + sc) = v;
    }
}

// ---------------------------------------------------------------------------
// Kernel 4: flash attention (R9 structure; only change: exp2f -> v_exp_f32).
// K/V double-buffered in padded LDS (TR=72), ONE barrier per kv-tile.
// P^T in registers via cvt_pk + permlane butterfly.
// ---------------------------------------------------------------------------
#define TR 72          // padded tile row, u16

__global__ __launch_bounds__(256, 4) void attn_kernel(
    const unsigned short* __restrict__ Qb, const unsigned short* __restrict__ Kb,
    const unsigned short* __restrict__ Vt, const float* __restrict__ mask,
    float* __restrict__ out)
{
    __shared__ union {
        struct {
            unsigned short Ks[2][64 * TR];     // 18432 B
            unsigned short Vs[2][64 * TR];     // 18432 B
        } s;                                    // 36864 B
        float oT[4][2][16][68];                 // 34816 B (epilogue)
    } u;

    int h  = blockIdx.x;
    int qt = blockIdx.y;
    int b  = blockIdx.z;
    int tid = threadIdx.x;
    int wave = tid >> 6, lane = tid & 63;
    int quad = lane >> 4, l15 = lane & 15;

    size_t bh = (size_t)(b * H_ + h);
    const unsigned short* Qp = Qb + bh * S_ * D_;
    const unsigned short* Kp = Kb + bh * S_ * D_;
    const unsigned short* Vp = Vt + bh * D_ * S_;
    const float* mp = mask + (size_t)b * S_;

    // Q B-frags (n=q, k=d), held in registers for the whole loop
    bf16x8 qb[2][2];
#pragma unroll
    for (int qg = 0; qg < 2; qg++)
#pragma unroll
        for (int hf = 0; hf < 2; hf++) {
            int qrow = qt * 128 + qg * 64 + wave * 16 + l15;
            qb[qg][hf] = *(const bf16x8*)(Qp + (size_t)qrow * D_ + hf * 32 + quad * 8);
        }

    f32x4 o[2][4] = {};
    float psum[2] = {0.0f, 0.0f};
    const float C2    = 0.03125f * 1.44269504f;   // (1/sqrt(1024)) * log2(e)
    const float LOG2E = 1.44269504f;

    // staging granules: rows 0..31 (e=tid) and 32..63 (e=tid+256); same col
    int sr0 = tid >> 3, sg0 = (tid & 7) * 8;
    int sr1 = sr0 + 32;

    // prologue: load tile 0 into regs
    u16x8 kr0 = *(const u16x8*)(Kp + (size_t)sr0 * D_ + sg0);
    u16x8 kr1 = *(const u16x8*)(Kp + (size_t)sr1 * D_ + sg0);
    u16x8 vr0 = *(const u16x8*)(Vp + (size_t)sr0 * S_ + sg0);
    u16x8 vr1 = *(const u16x8*)(Vp + (size_t)sr1 * S_ + sg0);

    int cur = 0;
    for (int kv0 = 0; kv0 < S_; kv0 += 64) {
        // stage current tile into buf[cur] (vmcnt drain happens here)
        *(u16x8*)&u.s.Ks[cur][sr0 * TR + sg0] = kr0;
        *(u16x8*)&u.s.Ks[cur][sr1 * TR + sg0] = kr1;
        *(u16x8*)&u.s.Vs[cur][sr0 * TR + sg0] = vr0;
        *(u16x8*)&u.s.Vs[cur][sr1 * TR + sg0] = vr1;
        __syncthreads();

        // issue next tile's global loads (drain overlaps compute below)
        int kvn = (kv0 + 64 < S_) ? kv0 + 64 : 0;
        kr0 = *(const u16x8*)(Kp + (size_t)(kvn + sr0) * D_ + sg0);
        kr1 = *(const u16x8*)(Kp + (size_t)(kvn + sr1) * D_ + sg0);
        vr0 = *(const u16x8*)(Vp + (size_t)sr0 * S_ + kvn + sg0);
        vr1 = *(const u16x8*)(Vp + (size_t)sr1 * S_ + kvn + sg0);

        const unsigned short* Ksc = u.s.Ks[cur];
        const unsigned short* Vsc = u.s.Vs[cur];

        // S^T: A = K rows (m=kv), B = Q (n=q); K-frags shared across q-groups
        f32x4 sa[2][4] = {};
        __builtin_amdgcn_s_setprio(1);
#pragma unroll
        for (int mt = 0; mt < 4; mt++) {
            bf16x8 kf0 = *(const bf16x8*)&Ksc[(mt * 16 + l15) * TR + quad * 8];
            bf16x8 kf1 = *(const bf16x8*)&Ksc[(mt * 16 + l15) * TR + 32 + quad * 8];
#pragma unroll
            for (int qg = 0; qg < 2; qg++) {
                sa[qg][mt] = __builtin_amdgcn_mfma_f32_16x16x32_bf16(kf0, qb[qg][0], sa[qg][mt], 0, 0, 0);
                sa[qg][mt] = __builtin_amdgcn_mfma_f32_16x16x32_bf16(kf1, qb[qg][1], sa[qg][mt], 0, 0, 0);
            }
        }
        __builtin_amdgcn_s_setprio(0);

        // p = exp2(s*C2 + mask*log2e); pack pairs to bf16 in-register
        unsigned pw[2][4][2];
#pragma unroll
        for (int mt = 0; mt < 4; mt++) {
            f32x4 mkv = *(const f32x4*)(mp + kv0 + mt * 16 + quad * 4);
#pragma unroll
            for (int qg = 0; qg < 2; qg++) {
                f32x4 pv;
#pragma unroll
                for (int r = 0; r < 4; r++)
                    pv[r] = fast_exp2(sa[qg][mt][r] * C2 + mkv[r] * LOG2E);
                psum[qg] += (pv[0] + pv[1]) + (pv[2] + pv[3]);
                asm("v_cvt_pk_bf16_f32 %0, %1, %2"
                    : "=v"(pw[qg][mt][0]) : "v"(pv[0]), "v"(pv[1]));
                asm("v_cvt_pk_bf16_f32 %0, %1, %2"
                    : "=v"(pw[qg][mt][1]) : "v"(pv[2]), "v"(pv[3]));
            }
        }

        // quad butterfly: pw[qg][mt][t] (lane qs holds kv=mt*16+qs*4+2t,+1)
        // -> pb[qg][hf] word t' = P^T[q=l15][kv=hf*32+quad*8+2t',+1]
        bf16x8 pb[2][2];
#pragma unroll
        for (int qg = 0; qg < 2; qg++)
#pragma unroll
            for (int hf = 0; hf < 2; hf++) {
                union { unsigned w[4]; bf16x8 v; } pbu;
#pragma unroll
                for (int t = 0; t < 2; t++) {
                    unsigned A = pw[qg][2 * hf + 0][t];
                    unsigned B = pw[qg][2 * hf + 1][t];
                    u32x2 r1 = __builtin_amdgcn_permlane32_swap(A, B, false, false);
                    u32x2 r2 = __builtin_amdgcn_permlane16_swap(r1[0], r1[1], false, false);
                    pbu.w[t]     = r2[0];
                    pbu.w[2 + t] = r2[1];
                }
                pb[qg][hf] = pbu.v;
            }

        // PV: A = V^T rows (m=d), B = P^T in registers; V-frags shared
        __builtin_amdgcn_s_setprio(1);
#pragma unroll
        for (int ct = 0; ct < 4; ct++) {
            bf16x8 vf0 = *(const bf16x8*)&Vsc[(ct * 16 + l15) * TR + quad * 8];
            bf16x8 vf1 = *(const bf16x8*)&Vsc[(ct * 16 + l15) * TR + 32 + quad * 8];
#pragma unroll
            for (int qg = 0; qg < 2; qg++) {
                o[qg][ct] = __builtin_amdgcn_mfma_f32_16x16x32_bf16(vf0, pb[qg][0], o[qg][ct], 0, 0, 0);
                o[qg][ct] = __builtin_amdgcn_mfma_f32_16x16x32_bf16(vf1, pb[qg][1], o[qg][ct], 0, 0, 0);
            }
        }
        __builtin_amdgcn_s_setprio(0);

        cur ^= 1;
    }
    __syncthreads();   // protect union reuse (oT overlaps Ks/Vs)

    // l reduction over the 4 quads (kv partitions), once
#pragma unroll
    for (int qg = 0; qg < 2; qg++) {
        psum[qg] += __shfl_xor(psum[qg], 16);
        psum[qg] += __shfl_xor(psum[qg], 32);
    }

    // epilogue: normalize, transpose via LDS, coalesced store
#pragma unroll
    for (int qg = 0; qg < 2; qg++) {
        float inv = 1.0f / psum[qg];
#pragma unroll
        for (int ct = 0; ct < 4; ct++) {
            float4 vv;
            vv.x = o[qg][ct][0] * inv; vv.y = o[qg][ct][1] * inv;
            vv.z = o[qg][ct][2] * inv; vv.w = o[qg][ct][3] * inv;
            *(float4*)&u.oT[wave][qg][l15][ct * 16 + quad * 4] = vv;
        }
    }
    __builtin_amdgcn_wave_barrier();
    {
        int qq = lane >> 2, d0 = (lane & 3) * 16;
#pragma unroll
        for (int qg = 0; qg < 2; qg++) {
            int s_abs = qt * 128 + qg * 64 + wave * 16 + qq;
            float* dst = out + ((size_t)b * S_ + s_abs) * (H_ * D_) + h * D_ + d0;
#pragma unroll
            for (int j = 0; j < 4; j++) {
                float4 vj = *(float4*)&u.oT[wave][qg][qq][d0 + j * 4];
                *(float4*)(dst + j * 4) = vj;
            }
        }
    }
}

// ---------------------------------------------------------------------------
extern "C" void kernel_launch(void* const* d_in, const int* in_sizes, int n_in,
                              void* d_out, int out_size, void* d_ws, size_t ws_size,
                              hipStream_t stream)
{
    const float* X    = (const float*)d_in[0];
    const float* Wq   = (const float*)d_in[1];
    const float* bq   = (const float*)d_in[2];
    const float* Wk   = (const float*)d_in[3];
    const float* bk   = (const float*)d_in[4];
    const float* Wv   = (const float*)d_in[5];
    const float* bv   = (const float*)d_in[6];
    const float* mask = (const float*)d_in[7];

    char* ws = (char*)d_ws;
    unsigned short* Xb = (unsigned short*)(ws);                      // 16 MB (reused as Vt)
    unsigned short* Wt = (unsigned short*)(ws + 16777216);           //  6 MB
    unsigned short* Qb = (unsigned short*)(ws + 23068672);           // 16 MB
    unsigned short* Kb = (unsigned short*)(ws + 39845888);           // 16 MB
    unsigned short* Vb = (unsigned short*)(ws + 56623104);           // 16 MB
    unsigned short* Vt = Xb;   // Xb dead after qkv_gemm; reuse for V^T

    float* tab = (float*)d_out;   // RoPE tables in ctx region (overwritten by attn)

    rope_table_kernel<<<dim3(131072 / 256), 256, 0, stream>>>(tab);
    cast_x_kernel<<<dim3(M_ * HID / 4 / 256), 256, 0, stream>>>(X, Xb);
    cast_wt_kernel<<<dim3(16, 16, 3), 256, 0, stream>>>(Wq, Wk, Wv, Wt);
    qkv_gemm_kernel<<<dim3(HID / BN, M_ / BM, 3), 256, 0, stream>>>(
        Xb, Wt, bq, bk, bv, tab, tab + 131072, (float*)d_out, Qb, Kb, Vb);
    transpose_v_kernel<<<dim3(S_ / 64, B_ * H_), 256, 0, stream>>>(Vb, Vt);
    attn_kernel<<<dim3(H_, S_ / 128, B_), 256, 0, stream>>>(
        Qb, Kb, Vt, mask, (float*)d_out);
}